// Round 1
// baseline (90.633 us; speedup 1.0000x reference)
//
#include <hip/hip_runtime.h>

#define N_TOT 4096
#define N_UPC 2048
#define HID 32
#define M_LUT 2048
#define ITILE 256
#define JCH 64

// LUT lives in device-global memory (no reliance on ws_size).
// Entry m of table t: (F(s_m), F(s_{m+1})-F(s_m)), s_m = m * 25/(M_LUT-1).
__device__ float2 g_lut[2 * M_LUT];

__device__ __forceinline__ float eval_F(float s, const float* __restrict__ w1,
                                        const float* __restrict__ b1,
                                        const float* __restrict__ wo, float bo) {
  // replicate reference numerics: r = sqrt(s+1e-15), xn = clip(r/5, 0, 1-1e-5)
  float r = sqrtf(s + 1e-15f);
  float xn = fminf(r * 0.2f, 1.0f - 1e-5f);
  float dcy = __expf(1.0f - 1.0f / (1.0f - xn * xn));
  float acc = bo;
#pragma unroll
  for (int k = 0; k < HID; ++k) {
    float z = fmaf(dcy, w1[k], b1[k]);
    float h = z / (1.0f + __expf(-z));  // swish
    acc = fmaf(h, wo[k], acc);
  }
  return acc * dcy;
}

// Kernel 1: build both LUTs and initialize out = rs.
__global__ void lut_init_kernel(const float* __restrict__ rs,
    const float* __restrict__ sw1, const float* __restrict__ sb1,
    const float* __restrict__ swo, const float* __restrict__ sbo,
    const float* __restrict__ dw1, const float* __restrict__ db1,
    const float* __restrict__ dwo, const float* __restrict__ dbo,
    float* __restrict__ out) {
  const float DSF = 25.0f / (float)(M_LUT - 1);
  int t = blockIdx.x * blockDim.x + threadIdx.x;
  if (t < 2 * M_LUT) {
    int tab = t >> 11;           // M_LUT = 2048
    int m = t & (M_LUT - 1);
    const float* w1 = tab ? dw1 : sw1;
    const float* b1 = tab ? db1 : sb1;
    const float* wo = tab ? dwo : swo;
    float bo = tab ? dbo[0] : sbo[0];
    float s0 = m * DSF;
    float f0 = eval_F(s0, w1, b1, wo, bo);
    float f1 = eval_F(s0 + DSF, w1, b1, wo, bo);
    g_lut[t] = make_float2(f0, f1 - f0);
  }
  if (t < 3 * N_TOT) out[t] = rs[t];   // out starts at rs; pair kernel adds backflow
}

// Kernel 2: 16 i-tiles x 64 j-chunks = 1024 blocks, 256 threads.
// Each thread owns one row i, loops over a 64-wide j chunk.
__global__ __launch_bounds__(256) void pair_kernel(const float* __restrict__ rs,
                                                   float* __restrict__ out) {
  __shared__ float2 lut[2 * M_LUT];    // 32 KB
  for (int t = threadIdx.x; t < 2 * M_LUT; t += ITILE) lut[t] = g_lut[t];

  int itile = blockIdx.x & 15;         // 16 i-tiles of 256
  int jc = blockIdx.x >> 4;            // 64 j-chunks of 64
  int i = itile * ITILE + threadIdx.x;
  float xi = rs[3 * i + 0];
  float yi = rs[3 * i + 1];
  float zi = rs[3 * i + 2];
  __syncthreads();

  // spin(i) is block-uniform (tiles 0-7 = up); j-chunk is entirely one spin.
  const bool same_spin = ((jc < (N_UPC / JCH)) == (itile < 8));
  const float2* __restrict__ tab = lut + (same_spin ? 0 : M_LUT);
  const float INV_DS = (float)(M_LUT - 1) / 25.0f;
  const float UMAX = (float)(M_LUT - 1);

  float ax = 0.f, ay = 0.f, az = 0.f;
  int j0 = jc * JCH;
#pragma unroll 8
  for (int jj = 0; jj < JCH; ++jj) {
    int j = j0 + jj;
    float dx = xi - rs[3 * j + 0];     // uniform address -> scalar-load friendly
    float dy = yi - rs[3 * j + 1];
    float dz = zi - rs[3 * j + 2];
    // min-image: d - 10*rint(d/10); differs from ref's mod only at |d|==5 where F==0
    dx = fmaf(-10.0f, rintf(dx * 0.1f), dx);
    dy = fmaf(-10.0f, rintf(dy * 0.1f), dy);
    dz = fmaf(-10.0f, rintf(dz * 0.1f), dz);
    float s = fmaf(dx, dx, fmaf(dy, dy, dz * dz));
    float u = fminf(s * INV_DS, UMAX); // s>=25 clamps into the exactly-zero tail
    int idx = (int)u;
    float w = u - (float)idx;
    float2 e = tab[idx];
    float F = fmaf(w, e.y, e.x);       // i==j: d=0 -> contribution 0 regardless of F
    ax = fmaf(F, dx, ax);
    ay = fmaf(F, dy, ay);
    az = fmaf(F, dz, az);
  }
  atomicAdd(&out[3 * i + 0], ax);
  atomicAdd(&out[3 * i + 1], ay);
  atomicAdd(&out[3 * i + 2], az);
}

extern "C" void kernel_launch(void* const* d_in, const int* in_sizes, int n_in,
                              void* d_out, int out_size, void* d_ws, size_t ws_size,
                              hipStream_t stream) {
  const float* rs = (const float*)d_in[0];
  lut_init_kernel<<<64, 256, 0, stream>>>(
      rs,
      (const float*)d_in[1], (const float*)d_in[2], (const float*)d_in[3],
      (const float*)d_in[4],
      (const float*)d_in[5], (const float*)d_in[6], (const float*)d_in[7],
      (const float*)d_in[8],
      (float*)d_out);
  pair_kernel<<<(N_TOT / ITILE) * (N_TOT / JCH), ITILE, 0, stream>>>(
      rs, (float*)d_out);
}